// Round 4
// baseline (514.034 us; speedup 1.0000x reference)
//
#include <hip/hip_runtime.h>

#define LEAKY 0.2f
#define SCAN_BS 256

__device__ __forceinline__ float lane_bcast(float v, int k) {
    return __int_as_float(__builtin_amdgcn_readlane(__float_as_int(v), k));
}

// ---------------------------------------------------------------- CSR build
__global__ __launch_bounds__(256) void hist_kernel(const int* __restrict__ row, int E,
                                                   int* __restrict__ deg) {
    int e = blockIdx.x * 256 + threadIdx.x;
    if (e < E) atomicAdd(&deg[row[e]], 1);
}

// phase 1: per-block sums of deg
__global__ __launch_bounds__(SCAN_BS) void bsum_kernel(const int* __restrict__ deg,
                                                       int* __restrict__ bsums, int n) {
    int i = blockIdx.x * SCAN_BS + threadIdx.x;
    int v = (i < n) ? deg[i] : 0;
    for (int off = 32; off; off >>= 1) v += __shfl_xor(v, off, 64);
    __shared__ int wsum[SCAN_BS / 64];
    int lane = threadIdx.x & 63, w = threadIdx.x >> 6;
    if (lane == 0) wsum[w] = v;
    __syncthreads();
    if (threadIdx.x == 0) {
        int s = 0;
#pragma unroll
        for (int j = 0; j < SCAN_BS / 64; ++j) s += wsum[j];
        bsums[blockIdx.x] = s;
    }
}

// phase 2: exclusive scan of block sums (nb <= 1024), single small block
__global__ __launch_bounds__(1024) void scan_bsums_kernel(int* __restrict__ bsums, int nb) {
    __shared__ int sh[1024];
    int tid = threadIdx.x;
    int v = (tid < nb) ? bsums[tid] : 0;
    sh[tid] = v;
    __syncthreads();
    for (int off = 1; off < 1024; off <<= 1) {
        int u = (tid >= off) ? sh[tid - off] : 0;
        __syncthreads();
        sh[tid] += u;
        __syncthreads();
    }
    if (tid < nb) bsums[tid] = sh[tid] - v;  // exclusive
}

// phase 3: in-block exclusive scan + block base; grid covers n+1 so rowptr[n]=E
__global__ __launch_bounds__(SCAN_BS) void rowptr_kernel(const int* __restrict__ deg,
                                                         const int* __restrict__ bsums_ex,
                                                         int* __restrict__ rowptr, int n) {
    __shared__ int sh[SCAN_BS];
    int tid = threadIdx.x;
    int i = blockIdx.x * SCAN_BS + tid;
    int v = (i < n) ? deg[i] : 0;
    sh[tid] = v;
    __syncthreads();
    for (int off = 1; off < SCAN_BS; off <<= 1) {
        int u = (tid >= off) ? sh[tid - off] : 0;
        __syncthreads();
        sh[tid] += u;
        __syncthreads();
    }
    if (i <= n) rowptr[i] = sh[tid] - v + bsums_ex[blockIdx.x];
}

__global__ __launch_bounds__(256) void dinv_kernel(const int* __restrict__ deg,
                                                   float* __restrict__ dinv, int n) {
    int i = blockIdx.x * 256 + threadIdx.x;
    if (i < n) {
        int d = deg[i];
        dinv[i] = d > 0 ? rsqrtf((float)d) : 0.0f;
    }
}

// scatter writes ONLY cols (norm factored out as scale[c] read in aggregate):
// halves the scattered-store line traffic.
__global__ __launch_bounds__(256) void scatter_kernel(const int* __restrict__ row,
                                                      const int* __restrict__ col, int E,
                                                      const int* __restrict__ rowptr,
                                                      int* __restrict__ cursor,
                                                      int* __restrict__ cols_s) {
    int e = blockIdx.x * 256 + threadIdx.x;
    if (e < E) {
        int r = row[e];
        int p = rowptr[r] + atomicAdd(&cursor[r], 1);
        cols_s[p] = col[e];
    }
}

// scale[n] = dinv[n] * len[n]  (edge weight contribution of source node n)
__global__ __launch_bounds__(256) void scale_kernel(const float* __restrict__ dinv,
                                                    const float* __restrict__ len,
                                                    float* __restrict__ scale, int n) {
    int i = blockIdx.x * 256 + threadIdx.x;
    if (i < n) scale[i] = dinv[i] * len[i];
}

// ---------------------------------------------------------------- aggregate
// one wave per node, lane = feature dim; 4 independent acc chains keep 4
// row-gathers in flight. agg[n] = dinv[n] * sum_e scale[c_e] * h_norm[c_e].
__global__ __launch_bounds__(256) void aggregate_kernel(const int* __restrict__ rowptr,
                                                        const int* __restrict__ cols_s,
                                                        const float* __restrict__ scale,
                                                        const float* __restrict__ dinv,
                                                        const float* __restrict__ h_norm,
                                                        int h_stride,
                                                        float* __restrict__ agg,
                                                        int n_nodes) {
    int lane = threadIdx.x & 63;
    int n = (blockIdx.x * blockDim.x + threadIdx.x) >> 6;
    if (n >= n_nodes) return;
    int nu = __builtin_amdgcn_readfirstlane(n);
    int s = rowptr[nu];
    int e = rowptr[nu + 1];
    float dn = dinv[nu];
    float acc0 = 0.0f, acc1 = 0.0f, acc2 = 0.0f, acc3 = 0.0f;
    int t = s;
    for (; t + 3 < e; t += 4) {
        int c0 = cols_s[t + 0];
        int c1 = cols_s[t + 1];
        int c2 = cols_s[t + 2];
        int c3 = cols_s[t + 3];
        float w0 = scale[c0];
        float w1 = scale[c1];
        float w2 = scale[c2];
        float w3 = scale[c3];
        acc0 = fmaf(w0, h_norm[(size_t)c0 * h_stride + lane], acc0);
        acc1 = fmaf(w1, h_norm[(size_t)c1 * h_stride + lane], acc1);
        acc2 = fmaf(w2, h_norm[(size_t)c2 * h_stride + lane], acc2);
        acc3 = fmaf(w3, h_norm[(size_t)c3 * h_stride + lane], acc3);
    }
    for (; t < e; ++t) {
        int c0 = cols_s[t];
        acc0 = fmaf(scale[c0], h_norm[(size_t)c0 * h_stride + lane], acc0);
    }
    agg[((size_t)n << 6) + lane] = dn * ((acc0 + acc1) + (acc2 + acc3));
}

// ---------------------------------------------------------------- transform
// lane = output dim d. W1/W2 columns in VGPRs. Per node: reconstruct
// un-normalized h = h_norm * len, dual 64-fma chains, leaky-gate, then fused
// l2-normalize (wave shfl_xor sum of squares). Writes normalized row to out
// and len[n] for the next layer's reconstruction.
#define NODES_PER_WAVE 16
__global__ __launch_bounds__(256, 3) void transform_kernel(const float* __restrict__ h_norm,
                                                           int h_stride,
                                                           const float* __restrict__ len_in,
                                                           const float* __restrict__ agg,
                                                           const float* __restrict__ w1,
                                                           const float* __restrict__ b1,
                                                           const float* __restrict__ w2,
                                                           const float* __restrict__ b2,
                                                           float* __restrict__ out_norm,
                                                           int ostride,
                                                           float* __restrict__ len_out,
                                                           int n_nodes) {
    int lane = threadIdx.x & 63;
    int wave = (blockIdx.x * blockDim.x + threadIdx.x) >> 6;

    float w1r[64], w2r[64];
#pragma unroll 64
    for (int k = 0; k < 64; ++k) {
        w1r[k] = w1[(k << 6) + lane];   // W1[k][d=lane], coalesced, L2-hot
        w2r[k] = w2[(k << 6) + lane];
    }
    float b1v = b1[lane];
    float b2v = b2[lane];

    int n0 = wave * NODES_PER_WAVE;
#pragma unroll 1
    for (int ni = 0; ni < NODES_PER_WAVE; ++ni) {
        int n = n0 + ni;
        if (n >= n_nodes) break;
        float lv = len_in ? len_in[n] : 1.0f;             // wave-uniform
        float av = agg[((size_t)n << 6) + lane];          // lane = k role
        float hv = h_norm[(size_t)n * h_stride + lane] * lv;
        float mv = av * hv;
        float acc1 = b1v;
        float acc2 = b2v;
#pragma unroll 64
        for (int k = 0; k < 64; ++k) {
            acc1 = fmaf(lane_bcast(av, k), w1r[k], acc1);
            acc2 = fmaf(lane_bcast(mv, k), w2r[k], acc2);
        }
        float v1 = acc1 > 0.0f ? acc1 : LEAKY * acc1;
        float v2 = acc2 > 0.0f ? acc2 : LEAKY * acc2;
        float v = v1 + v2;
        float sq = v * v;
        for (int off = 32; off; off >>= 1) sq += __shfl_xor(sq, off, 64);
        float m = fmaxf(sq, 1e-12f);
        float inv = rsqrtf(m);
        out_norm[(size_t)n * ostride + lane] = v * inv;   // lane = d role
        if (lane == 0) len_out[n] = sqrtf(m);
    }
}

// ---------------------------------------------------------------- copy x -> slot 0
__global__ __launch_bounds__(256) void copyx_kernel(const float* __restrict__ x,
                                                    float* __restrict__ out,
                                                    int n_nodes, int nslots) {
    int t = blockIdx.x * 256 + threadIdx.x;
    int total = n_nodes * 16;                 // 16 float4 per node row
    if (t >= total) return;
    int node = t >> 4;
    int j = t & 15;
    const float4* src = reinterpret_cast<const float4*>(x);
    float4* dst = reinterpret_cast<float4*>(out);
    dst[(size_t)node * (nslots * 16) + j] = src[(size_t)node * 16 + j];
}

// ---------------------------------------------------------------- launch
extern "C" void kernel_launch(void* const* d_in, const int* in_sizes, int n_in,
                              void* d_out, int out_size, void* d_ws, size_t ws_size,
                              hipStream_t stream) {
    const float* x  = (const float*)d_in[0];
    const int*  edge = (const int*)d_in[1];
    const float* W1 = (const float*)d_in[2];
    const float* b1 = (const float*)d_in[3];
    const float* W2 = (const float*)d_in[4];
    const float* b2 = (const float*)d_in[5];

    const int N = in_sizes[0] / 64;
    const int E = in_sizes[1] / 2;
    const int K = in_sizes[2] / 4096;
    const int nslots = K + 1;
    const int ostride = nslots * 64;

    const int* row = edge;
    const int* col = edge + E;
    float* out = (float*)d_out;

    // workspace carve-up (all 256B aligned); ~33 MB total
    char* ws = (char*)d_ws;
    size_t off = 0;
    auto carve = [&](size_t bytes) -> void* {
        void* p = ws + off;
        off = (off + bytes + 255) & ~(size_t)255;
        return p;
    };
    int*   deg     = (int*)  carve((size_t)N * 4);
    int*   rowptr  = (int*)  carve((size_t)(N + 1) * 4);
    int*   cursor  = (int*)  carve((size_t)N * 4);
    float* dinv    = (float*)carve((size_t)N * 4);
    float* scale   = (float*)carve((size_t)N * 4);
    float* len     = (float*)carve((size_t)N * 4);
    int*   cols_s  = (int*)  carve((size_t)E * 4);
    float* agg     = (float*)carve((size_t)N * 64 * 4);
    int*   bsums   = (int*)  carve(2048 * 4);
    (void)ws_size;

    hipMemsetAsync(deg, 0, (size_t)N * 4, stream);
    hipMemsetAsync(cursor, 0, (size_t)N * 4, stream);

    hist_kernel<<<(E + 255) / 256, 256, 0, stream>>>(row, E, deg);

    // hierarchical exclusive scan: deg -> rowptr (grid covers N+1 for rowptr[N]=E)
    const int nb = (N + 1 + SCAN_BS - 1) / SCAN_BS;
    bsum_kernel<<<nb, SCAN_BS, 0, stream>>>(deg, bsums, N);
    scan_bsums_kernel<<<1, 1024, 0, stream>>>(bsums, nb);
    rowptr_kernel<<<nb, SCAN_BS, 0, stream>>>(deg, bsums, rowptr, N);

    dinv_kernel<<<(N + 255) / 256, 256, 0, stream>>>(deg, dinv, N);
    scatter_kernel<<<(E + 255) / 256, 256, 0, stream>>>(row, col, E, rowptr, cursor, cols_s);

    copyx_kernel<<<(N * 16 + 255) / 256, 256, 0, stream>>>(x, out, N, nslots);

    const int waves_needed = (N + NODES_PER_WAVE - 1) / NODES_PER_WAVE;
    const int tblocks = (waves_needed + 3) / 4;
    const int nblk256 = (N + 255) / 256;

    for (int i = 0; i < K; ++i) {
        const float* h_norm;
        int h_stride;
        const float* len_in;
        const float* sc;
        if (i == 0) {
            h_norm = x; h_stride = 64; len_in = nullptr; sc = dinv;
        } else {
            h_norm = out + (size_t)i * 64; h_stride = ostride; len_in = len;
            scale_kernel<<<nblk256, 256, 0, stream>>>(dinv, len, scale, N);
            sc = scale;
        }
        aggregate_kernel<<<(N * 64 + 255) / 256, 256, 0, stream>>>(rowptr, cols_s, sc, dinv,
                                                                   h_norm, h_stride, agg, N);
        transform_kernel<<<tblocks, 256, 0, stream>>>(h_norm, h_stride, len_in, agg,
                                                      W1 + (size_t)i * 4096,
                                                      b1 + (size_t)i * 64,
                                                      W2 + (size_t)i * 4096,
                                                      b2 + (size_t)i * 64,
                                                      out + (size_t)(i + 1) * 64,
                                                      ostride, len, N);
    }
}

// Round 5
// 375.603 us; speedup vs baseline: 1.3686x; 1.3686x over previous
//
#include <hip/hip_runtime.h>

#define LEAKY 0.2f
#define SCAN_BS 256

typedef __attribute__((ext_vector_type(8))) short bf16x8;
typedef __attribute__((ext_vector_type(4))) float f32x4;

__device__ __forceinline__ unsigned short f2bf(float f) {
    unsigned u = __float_as_uint(f);
    u += 0x7FFF + ((u >> 16) & 1);          // RTNE
    return (unsigned short)(u >> 16);
}

// ---------------------------------------------------------------- CSR build
__global__ __launch_bounds__(256) void hist_kernel(const int* __restrict__ row, int E,
                                                   int* __restrict__ deg) {
    int e = blockIdx.x * 256 + threadIdx.x;
    if (e < E) atomicAdd(&deg[row[e]], 1);
}

__global__ __launch_bounds__(SCAN_BS) void bsum_kernel(const int* __restrict__ deg,
                                                       int* __restrict__ bsums, int n) {
    int i = blockIdx.x * SCAN_BS + threadIdx.x;
    int v = (i < n) ? deg[i] : 0;
    for (int off = 32; off; off >>= 1) v += __shfl_xor(v, off, 64);
    __shared__ int wsum[SCAN_BS / 64];
    int lane = threadIdx.x & 63, w = threadIdx.x >> 6;
    if (lane == 0) wsum[w] = v;
    __syncthreads();
    if (threadIdx.x == 0) {
        int s = 0;
#pragma unroll
        for (int j = 0; j < SCAN_BS / 64; ++j) s += wsum[j];
        bsums[blockIdx.x] = s;
    }
}

__global__ __launch_bounds__(1024) void scan_bsums_kernel(int* __restrict__ bsums, int nb) {
    __shared__ int sh[1024];
    int tid = threadIdx.x;
    int v = (tid < nb) ? bsums[tid] : 0;
    sh[tid] = v;
    __syncthreads();
    for (int off = 1; off < 1024; off <<= 1) {
        int u = (tid >= off) ? sh[tid - off] : 0;
        __syncthreads();
        sh[tid] += u;
        __syncthreads();
    }
    if (tid < nb) bsums[tid] = sh[tid] - v;  // exclusive
}

__global__ __launch_bounds__(SCAN_BS) void rowptr_kernel(const int* __restrict__ deg,
                                                         const int* __restrict__ bsums_ex,
                                                         int* __restrict__ rowptr, int n) {
    __shared__ int sh[SCAN_BS];
    int tid = threadIdx.x;
    int i = blockIdx.x * SCAN_BS + tid;
    int v = (i < n) ? deg[i] : 0;
    sh[tid] = v;
    __syncthreads();
    for (int off = 1; off < SCAN_BS; off <<= 1) {
        int u = (tid >= off) ? sh[tid - off] : 0;
        __syncthreads();
        sh[tid] += u;
        __syncthreads();
    }
    if (i <= n) rowptr[i] = sh[tid] - v + bsums_ex[blockIdx.x];
}

__global__ __launch_bounds__(256) void dinv_kernel(const int* __restrict__ deg,
                                                   float* __restrict__ dinv, int n) {
    int i = blockIdx.x * 256 + threadIdx.x;
    if (i < n) {
        int d = deg[i];
        dinv[i] = d > 0 ? rsqrtf((float)d) : 0.0f;
    }
}

__global__ __launch_bounds__(256) void scatter_kernel(const int* __restrict__ row,
                                                      const int* __restrict__ col, int E,
                                                      const int* __restrict__ rowptr,
                                                      int* __restrict__ cursor,
                                                      int* __restrict__ cols_s) {
    int e = blockIdx.x * 256 + threadIdx.x;
    if (e < E) {
        int r = row[e];
        int p = rowptr[r] + atomicAdd(&cursor[r], 1);
        cols_s[p] = col[e];
    }
}

__global__ __launch_bounds__(256) void scale_kernel(const float* __restrict__ dinv,
                                                    const float* __restrict__ len,
                                                    float* __restrict__ scale, int n) {
    int i = blockIdx.x * 256 + threadIdx.x;
    if (i < n) scale[i] = dinv[i] * len[i];
}

// ---------------------------------------------------------------- aggregate
__global__ __launch_bounds__(256) void aggregate_kernel(const int* __restrict__ rowptr,
                                                        const int* __restrict__ cols_s,
                                                        const float* __restrict__ scale,
                                                        const float* __restrict__ dinv,
                                                        const float* __restrict__ h_norm,
                                                        int h_stride,
                                                        float* __restrict__ agg,
                                                        int n_nodes) {
    int lane = threadIdx.x & 63;
    int n = (blockIdx.x * blockDim.x + threadIdx.x) >> 6;
    if (n >= n_nodes) return;
    int nu = __builtin_amdgcn_readfirstlane(n);
    int s = rowptr[nu];
    int e = rowptr[nu + 1];
    float dn = dinv[nu];
    float acc0 = 0.0f, acc1 = 0.0f, acc2 = 0.0f, acc3 = 0.0f;
    int t = s;
    for (; t + 3 < e; t += 4) {
        int c0 = cols_s[t + 0];
        int c1 = cols_s[t + 1];
        int c2 = cols_s[t + 2];
        int c3 = cols_s[t + 3];
        float w0 = scale[c0];
        float w1 = scale[c1];
        float w2 = scale[c2];
        float w3 = scale[c3];
        acc0 = fmaf(w0, h_norm[(size_t)c0 * h_stride + lane], acc0);
        acc1 = fmaf(w1, h_norm[(size_t)c1 * h_stride + lane], acc1);
        acc2 = fmaf(w2, h_norm[(size_t)c2 * h_stride + lane], acc2);
        acc3 = fmaf(w3, h_norm[(size_t)c3 * h_stride + lane], acc3);
    }
    for (; t < e; ++t) {
        int c0 = cols_s[t];
        acc0 = fmaf(scale[c0], h_norm[(size_t)c0 * h_stride + lane], acc0);
    }
    agg[((size_t)n << 6) + lane] = dn * ((acc0 + acc1) + (acc2 + acc3));
}

// ---------------------------------------------------------------- transform (MFMA)
// One wave = 16-node x 64-dim output tile. C1 = A*W1, C2 = M*W2 with
// A = agg tile, M = agg .* (h_norm*len), via v_mfma_f32_16x16x32_bf16:
// A frag: [l&15][8*(l>>4)+j] (8 contiguous k); B frag: [8*(l>>4)+j][l&15];
// C: col = l&15, row = 4*(l>>4)+reg. f32 accumulate; f32 epilogue
// (bias + leaky + fused l2-normalize via 16-lane shfl_xor reduce).
__global__ __launch_bounds__(256, 3) void transform_kernel(const float* __restrict__ h_norm,
                                                           int h_stride,
                                                           const float* __restrict__ len_in,
                                                           const float* __restrict__ agg,
                                                           const float* __restrict__ w1,
                                                           const float* __restrict__ b1,
                                                           const float* __restrict__ w2,
                                                           const float* __restrict__ b2,
                                                           float* __restrict__ out_norm,
                                                           int ostride,
                                                           float* __restrict__ len_out,
                                                           int n_nodes) {
    int lane = threadIdx.x & 63;
    int wave = (blockIdx.x * blockDim.x + threadIdx.x) >> 6;
    int n0 = wave * 16;
    if (n0 >= n_nodes) return;

    int r16 = lane & 15;   // A row / B,C col within tile
    int g   = lane >> 4;   // k-group

    // B fragments from global (W is 32 KB total -> L1/L2-hot)
    bf16x8 w1f[2][4], w2f[2][4];
#pragma unroll
    for (int kt = 0; kt < 2; ++kt) {
#pragma unroll
        for (int dt = 0; dt < 4; ++dt) {
            const float* p1 = w1 + (kt * 32 + 8 * g) * 64 + dt * 16 + r16;
            const float* p2 = w2 + (kt * 32 + 8 * g) * 64 + dt * 16 + r16;
            bf16x8 f1, f2;
#pragma unroll
            for (int j = 0; j < 8; ++j) {
                f1[j] = (short)f2bf(p1[(size_t)j * 64]);
                f2[j] = (short)f2bf(p2[(size_t)j * 64]);
            }
            w1f[kt][dt] = f1;
            w2f[kt][dt] = f2;
        }
    }

    int row = n0 + r16;
    if (row >= n_nodes) row = n_nodes - 1;          // clamp for tail tile
    float lv = len_in ? len_in[row] : 1.0f;

    f32x4 acc1[4], acc2[4];
#pragma unroll
    for (int dt = 0; dt < 4; ++dt) {
        acc1[dt] = (f32x4){0.0f, 0.0f, 0.0f, 0.0f};
        acc2[dt] = (f32x4){0.0f, 0.0f, 0.0f, 0.0f};
    }

#pragma unroll
    for (int kt = 0; kt < 2; ++kt) {
        const float* ap = agg + ((size_t)row << 6) + kt * 32 + 8 * g;
        const float* hp = h_norm + (size_t)row * h_stride + kt * 32 + 8 * g;
        float4 a0 = *reinterpret_cast<const float4*>(ap);
        float4 a1 = *reinterpret_cast<const float4*>(ap + 4);
        float4 h0 = *reinterpret_cast<const float4*>(hp);
        float4 h1 = *reinterpret_cast<const float4*>(hp + 4);
        bf16x8 af, mf;
        af[0] = (short)f2bf(a0.x); af[1] = (short)f2bf(a0.y);
        af[2] = (short)f2bf(a0.z); af[3] = (short)f2bf(a0.w);
        af[4] = (short)f2bf(a1.x); af[5] = (short)f2bf(a1.y);
        af[6] = (short)f2bf(a1.z); af[7] = (short)f2bf(a1.w);
        mf[0] = (short)f2bf(a0.x * h0.x * lv); mf[1] = (short)f2bf(a0.y * h0.y * lv);
        mf[2] = (short)f2bf(a0.z * h0.z * lv); mf[3] = (short)f2bf(a0.w * h0.w * lv);
        mf[4] = (short)f2bf(a1.x * h1.x * lv); mf[5] = (short)f2bf(a1.y * h1.y * lv);
        mf[6] = (short)f2bf(a1.z * h1.z * lv); mf[7] = (short)f2bf(a1.w * h1.w * lv);
#pragma unroll
        for (int dt = 0; dt < 4; ++dt) {
            acc1[dt] = __builtin_amdgcn_mfma_f32_16x16x32_bf16(af, w1f[kt][dt], acc1[dt], 0, 0, 0);
            acc2[dt] = __builtin_amdgcn_mfma_f32_16x16x32_bf16(mf, w2f[kt][dt], acc2[dt], 0, 0, 0);
        }
    }

    // epilogue: bias + leaky + sum, fused l2-normalize per output row
    float b1v[4], b2v[4];
#pragma unroll
    for (int dt = 0; dt < 4; ++dt) {
        b1v[dt] = b1[dt * 16 + r16];
        b2v[dt] = b2[dt * 16 + r16];
    }
    float v[4][4];  // [dt][reg]
#pragma unroll
    for (int dt = 0; dt < 4; ++dt) {
#pragma unroll
        for (int reg = 0; reg < 4; ++reg) {
            float x1 = acc1[dt][reg] + b1v[dt];
            float x2 = acc2[dt][reg] + b2v[dt];
            x1 = x1 > 0.0f ? x1 : LEAKY * x1;
            x2 = x2 > 0.0f ? x2 : LEAKY * x2;
            v[dt][reg] = x1 + x2;
        }
    }
#pragma unroll
    for (int reg = 0; reg < 4; ++reg) {
        float sq = v[0][reg] * v[0][reg] + v[1][reg] * v[1][reg] +
                   v[2][reg] * v[2][reg] + v[3][reg] * v[3][reg];
        sq += __shfl_xor(sq, 1, 64);
        sq += __shfl_xor(sq, 2, 64);
        sq += __shfl_xor(sq, 4, 64);
        sq += __shfl_xor(sq, 8, 64);
        float m = fmaxf(sq, 1e-12f);
        float inv = rsqrtf(m);
        int orow = n0 + 4 * g + reg;
        if (orow < n_nodes) {
#pragma unroll
            for (int dt = 0; dt < 4; ++dt)
                out_norm[(size_t)orow * ostride + dt * 16 + r16] = v[dt][reg] * inv;
            if (r16 == reg) len_out[orow] = sqrtf(m);
        }
    }
}

// ---------------------------------------------------------------- copy x -> slot 0
__global__ __launch_bounds__(256) void copyx_kernel(const float* __restrict__ x,
                                                    float* __restrict__ out,
                                                    int n_nodes, int nslots) {
    int t = blockIdx.x * 256 + threadIdx.x;
    int total = n_nodes * 16;                 // 16 float4 per node row
    if (t >= total) return;
    int node = t >> 4;
    int j = t & 15;
    const float4* src = reinterpret_cast<const float4*>(x);
    float4* dst = reinterpret_cast<float4*>(out);
    dst[(size_t)node * (nslots * 16) + j] = src[(size_t)node * 16 + j];
}

// ---------------------------------------------------------------- launch
extern "C" void kernel_launch(void* const* d_in, const int* in_sizes, int n_in,
                              void* d_out, int out_size, void* d_ws, size_t ws_size,
                              hipStream_t stream) {
    const float* x  = (const float*)d_in[0];
    const int*  edge = (const int*)d_in[1];
    const float* W1 = (const float*)d_in[2];
    const float* b1 = (const float*)d_in[3];
    const float* W2 = (const float*)d_in[4];
    const float* b2 = (const float*)d_in[5];

    const int N = in_sizes[0] / 64;
    const int E = in_sizes[1] / 2;
    const int K = in_sizes[2] / 4096;
    const int nslots = K + 1;
    const int ostride = nslots * 64;

    const int* row = edge;
    const int* col = edge + E;
    float* out = (float*)d_out;

    char* ws = (char*)d_ws;
    size_t off = 0;
    auto carve = [&](size_t bytes) -> void* {
        void* p = ws + off;
        off = (off + bytes + 255) & ~(size_t)255;
        return p;
    };
    int*   deg     = (int*)  carve((size_t)N * 4);
    int*   rowptr  = (int*)  carve((size_t)(N + 1) * 4);
    int*   cursor  = (int*)  carve((size_t)N * 4);
    float* dinv    = (float*)carve((size_t)N * 4);
    float* scale   = (float*)carve((size_t)N * 4);
    float* len     = (float*)carve((size_t)N * 4);
    int*   cols_s  = (int*)  carve((size_t)E * 4);
    float* agg     = (float*)carve((size_t)N * 64 * 4);
    int*   bsums   = (int*)  carve(2048 * 4);
    (void)ws_size;

    hipMemsetAsync(deg, 0, (size_t)N * 4, stream);
    hipMemsetAsync(cursor, 0, (size_t)N * 4, stream);

    hist_kernel<<<(E + 255) / 256, 256, 0, stream>>>(row, E, deg);

    const int nb = (N + 1 + SCAN_BS - 1) / SCAN_BS;
    bsum_kernel<<<nb, SCAN_BS, 0, stream>>>(deg, bsums, N);
    scan_bsums_kernel<<<1, 1024, 0, stream>>>(bsums, nb);
    rowptr_kernel<<<nb, SCAN_BS, 0, stream>>>(deg, bsums, rowptr, N);

    dinv_kernel<<<(N + 255) / 256, 256, 0, stream>>>(deg, dinv, N);
    scatter_kernel<<<(E + 255) / 256, 256, 0, stream>>>(row, col, E, rowptr, cursor, cols_s);

    copyx_kernel<<<(N * 16 + 255) / 256, 256, 0, stream>>>(x, out, N, nslots);

    const int waves_needed = (N + 15) / 16;
    const int tblocks = (waves_needed + 3) / 4;
    const int nblk256 = (N + 255) / 256;

    for (int i = 0; i < K; ++i) {
        const float* h_norm;
        int h_stride;
        const float* len_in;
        const float* sc;
        if (i == 0) {
            h_norm = x; h_stride = 64; len_in = nullptr; sc = dinv;
        } else {
            h_norm = out + (size_t)i * 64; h_stride = ostride; len_in = len;
            scale_kernel<<<nblk256, 256, 0, stream>>>(dinv, len, scale, N);
            sc = scale;
        }
        aggregate_kernel<<<(N * 64 + 255) / 256, 256, 0, stream>>>(rowptr, cols_s, sc, dinv,
                                                                   h_norm, h_stride, agg, N);
        transform_kernel<<<tblocks, 256, 0, stream>>>(h_norm, h_stride, len_in, agg,
                                                      W1 + (size_t)i * 4096,
                                                      b1 + (size_t)i * 64,
                                                      W2 + (size_t)i * 4096,
                                                      b2 + (size_t)i * 64,
                                                      out + (size_t)(i + 1) * 64,
                                                      ostride, len, N);
    }
}

// Round 6
// 366.950 us; speedup vs baseline: 1.4008x; 1.0236x over previous
//
#include <hip/hip_runtime.h>

#define LEAKY 0.2f
#define SCAN_BS 256

typedef __attribute__((ext_vector_type(8))) short bf16x8;
typedef __attribute__((ext_vector_type(4))) float f32x4;

__device__ __forceinline__ unsigned short f2bf(float f) {
    unsigned u = __float_as_uint(f);
    u += 0x7FFF + ((u >> 16) & 1);          // RTNE
    return (unsigned short)(u >> 16);
}

// ---------------------------------------------------------------- CSR build
// 8 edges per thread: vector loads + 8 independent atomics in flight.
__global__ __launch_bounds__(256) void hist_kernel(const int* __restrict__ row, int E,
                                                   int* __restrict__ deg) {
    int base = (blockIdx.x * 256 + threadIdx.x) * 8;
    if (base + 8 <= E) {
        int4 r0 = *reinterpret_cast<const int4*>(row + base);
        int4 r1 = *reinterpret_cast<const int4*>(row + base + 4);
        atomicAdd(&deg[r0.x], 1); atomicAdd(&deg[r0.y], 1);
        atomicAdd(&deg[r0.z], 1); atomicAdd(&deg[r0.w], 1);
        atomicAdd(&deg[r1.x], 1); atomicAdd(&deg[r1.y], 1);
        atomicAdd(&deg[r1.z], 1); atomicAdd(&deg[r1.w], 1);
    } else {
        for (int e = base; e < E; ++e) atomicAdd(&deg[row[e]], 1);
    }
}

__global__ __launch_bounds__(SCAN_BS) void bsum_kernel(const int* __restrict__ deg,
                                                       int* __restrict__ bsums, int n) {
    int i = blockIdx.x * SCAN_BS + threadIdx.x;
    int v = (i < n) ? deg[i] : 0;
    for (int off = 32; off; off >>= 1) v += __shfl_xor(v, off, 64);
    __shared__ int wsum[SCAN_BS / 64];
    int lane = threadIdx.x & 63, w = threadIdx.x >> 6;
    if (lane == 0) wsum[w] = v;
    __syncthreads();
    if (threadIdx.x == 0) {
        int s = 0;
#pragma unroll
        for (int j = 0; j < SCAN_BS / 64; ++j) s += wsum[j];
        bsums[blockIdx.x] = s;
    }
}

__global__ __launch_bounds__(1024) void scan_bsums_kernel(int* __restrict__ bsums, int nb) {
    __shared__ int sh[1024];
    int tid = threadIdx.x;
    int v = (tid < nb) ? bsums[tid] : 0;
    sh[tid] = v;
    __syncthreads();
    for (int off = 1; off < 1024; off <<= 1) {
        int u = (tid >= off) ? sh[tid - off] : 0;
        __syncthreads();
        sh[tid] += u;
        __syncthreads();
    }
    if (tid < nb) bsums[tid] = sh[tid] - v;  // exclusive
}

__global__ __launch_bounds__(SCAN_BS) void rowptr_kernel(const int* __restrict__ deg,
                                                         const int* __restrict__ bsums_ex,
                                                         int* __restrict__ rowptr, int n) {
    __shared__ int sh[SCAN_BS];
    int tid = threadIdx.x;
    int i = blockIdx.x * SCAN_BS + tid;
    int v = (i < n) ? deg[i] : 0;
    sh[tid] = v;
    __syncthreads();
    for (int off = 1; off < SCAN_BS; off <<= 1) {
        int u = (tid >= off) ? sh[tid - off] : 0;
        __syncthreads();
        sh[tid] += u;
        __syncthreads();
    }
    if (i <= n) rowptr[i] = sh[tid] - v + bsums_ex[blockIdx.x];
}

__global__ __launch_bounds__(256) void dinv_kernel(const int* __restrict__ deg,
                                                   float* __restrict__ dinv, int n) {
    int i = blockIdx.x * 256 + threadIdx.x;
    if (i < n) {
        int d = deg[i];
        dinv[i] = d > 0 ? rsqrtf((float)d) : 0.0f;
    }
}

// 8 edges per thread: 8 independent {rowptr load, cursor atomic, store} chains.
__global__ __launch_bounds__(256) void scatter_kernel(const int* __restrict__ row,
                                                      const int* __restrict__ col, int E,
                                                      const int* __restrict__ rowptr,
                                                      int* __restrict__ cursor,
                                                      int* __restrict__ cols_s) {
    int base = (blockIdx.x * 256 + threadIdx.x) * 8;
    if (base + 8 <= E) {
        int4 r0 = *reinterpret_cast<const int4*>(row + base);
        int4 r1 = *reinterpret_cast<const int4*>(row + base + 4);
        int4 c0 = *reinterpret_cast<const int4*>(col + base);
        int4 c1 = *reinterpret_cast<const int4*>(col + base + 4);
        int rr[8] = {r0.x, r0.y, r0.z, r0.w, r1.x, r1.y, r1.z, r1.w};
        int cc[8] = {c0.x, c0.y, c0.z, c0.w, c1.x, c1.y, c1.z, c1.w};
        int bp[8], of[8];
#pragma unroll
        for (int j = 0; j < 8; ++j) bp[j] = rowptr[rr[j]];
#pragma unroll
        for (int j = 0; j < 8; ++j) of[j] = atomicAdd(&cursor[rr[j]], 1);
#pragma unroll
        for (int j = 0; j < 8; ++j) cols_s[bp[j] + of[j]] = cc[j];
    } else {
        for (int e = base; e < E; ++e) {
            int r = row[e];
            int p = rowptr[r] + atomicAdd(&cursor[r], 1);
            cols_s[p] = col[e];
        }
    }
}

__global__ __launch_bounds__(256) void scale_kernel(const float* __restrict__ dinv,
                                                    const float* __restrict__ len,
                                                    float* __restrict__ scale, int n) {
    int i = blockIdx.x * 256 + threadIdx.x;
    if (i < n) scale[i] = dinv[i] * len[i];
}

// ---------------------------------------------------------------- aggregate
// one wave per node, lane = feature dim; 8 independent 256B row-gathers in
// flight per wave (cols/scale are wave-uniform -> scalar loads).
__global__ __launch_bounds__(256) void aggregate_kernel(const int* __restrict__ rowptr,
                                                        const int* __restrict__ cols_s,
                                                        const float* __restrict__ scale,
                                                        const float* __restrict__ dinv,
                                                        const float* __restrict__ h_norm,
                                                        int h_stride,
                                                        float* __restrict__ agg,
                                                        int n_nodes) {
    int lane = threadIdx.x & 63;
    int n = (blockIdx.x * blockDim.x + threadIdx.x) >> 6;
    if (n >= n_nodes) return;
    int nu = __builtin_amdgcn_readfirstlane(n);
    int s = rowptr[nu];
    int e = rowptr[nu + 1];
    float dn = dinv[nu];
    float acc0 = 0.0f, acc1 = 0.0f, acc2 = 0.0f, acc3 = 0.0f;
    int t = s;
    for (; t + 7 < e; t += 8) {
        int c[8];
        float w[8];
#pragma unroll
        for (int j = 0; j < 8; ++j) c[j] = cols_s[t + j];
#pragma unroll
        for (int j = 0; j < 8; ++j) w[j] = scale[c[j]];
        float hv[8];
#pragma unroll
        for (int j = 0; j < 8; ++j) hv[j] = h_norm[(size_t)c[j] * h_stride + lane];
        acc0 = fmaf(w[0], hv[0], acc0);
        acc1 = fmaf(w[1], hv[1], acc1);
        acc2 = fmaf(w[2], hv[2], acc2);
        acc3 = fmaf(w[3], hv[3], acc3);
        acc0 = fmaf(w[4], hv[4], acc0);
        acc1 = fmaf(w[5], hv[5], acc1);
        acc2 = fmaf(w[6], hv[6], acc2);
        acc3 = fmaf(w[7], hv[7], acc3);
    }
    if (t + 3 < e) {
        int c0 = cols_s[t + 0];
        int c1 = cols_s[t + 1];
        int c2 = cols_s[t + 2];
        int c3 = cols_s[t + 3];
        float w0 = scale[c0];
        float w1 = scale[c1];
        float w2 = scale[c2];
        float w3 = scale[c3];
        acc0 = fmaf(w0, h_norm[(size_t)c0 * h_stride + lane], acc0);
        acc1 = fmaf(w1, h_norm[(size_t)c1 * h_stride + lane], acc1);
        acc2 = fmaf(w2, h_norm[(size_t)c2 * h_stride + lane], acc2);
        acc3 = fmaf(w3, h_norm[(size_t)c3 * h_stride + lane], acc3);
        t += 4;
    }
    for (; t < e; ++t) {
        int c0 = cols_s[t];
        acc0 = fmaf(scale[c0], h_norm[(size_t)c0 * h_stride + lane], acc0);
    }
    agg[((size_t)n << 6) + lane] = dn * ((acc0 + acc1) + (acc2 + acc3));
}

// ---------------------------------------------------------------- transform (MFMA)
// One wave = 16-node x 64-dim output tile. C1 = A*W1, C2 = M*W2 with
// A = agg tile, M = agg .* (h_norm*len), via v_mfma_f32_16x16x32_bf16.
__global__ __launch_bounds__(256, 3) void transform_kernel(const float* __restrict__ h_norm,
                                                           int h_stride,
                                                           const float* __restrict__ len_in,
                                                           const float* __restrict__ agg,
                                                           const float* __restrict__ w1,
                                                           const float* __restrict__ b1,
                                                           const float* __restrict__ w2,
                                                           const float* __restrict__ b2,
                                                           float* __restrict__ out_norm,
                                                           int ostride,
                                                           float* __restrict__ len_out,
                                                           int n_nodes) {
    int lane = threadIdx.x & 63;
    int wave = (blockIdx.x * blockDim.x + threadIdx.x) >> 6;
    int n0 = wave * 16;
    if (n0 >= n_nodes) return;

    int r16 = lane & 15;   // A row / B,C col within tile
    int g   = lane >> 4;   // k-group

    bf16x8 w1f[2][4], w2f[2][4];
#pragma unroll
    for (int kt = 0; kt < 2; ++kt) {
#pragma unroll
        for (int dt = 0; dt < 4; ++dt) {
            const float* p1 = w1 + (kt * 32 + 8 * g) * 64 + dt * 16 + r16;
            const float* p2 = w2 + (kt * 32 + 8 * g) * 64 + dt * 16 + r16;
            bf16x8 f1, f2;
#pragma unroll
            for (int j = 0; j < 8; ++j) {
                f1[j] = (short)f2bf(p1[(size_t)j * 64]);
                f2[j] = (short)f2bf(p2[(size_t)j * 64]);
            }
            w1f[kt][dt] = f1;
            w2f[kt][dt] = f2;
        }
    }

    int row = n0 + r16;
    if (row >= n_nodes) row = n_nodes - 1;          // clamp for tail tile
    float lv = len_in ? len_in[row] : 1.0f;

    f32x4 acc1[4], acc2[4];
#pragma unroll
    for (int dt = 0; dt < 4; ++dt) {
        acc1[dt] = (f32x4){0.0f, 0.0f, 0.0f, 0.0f};
        acc2[dt] = (f32x4){0.0f, 0.0f, 0.0f, 0.0f};
    }

#pragma unroll
    for (int kt = 0; kt < 2; ++kt) {
        const float* ap = agg + ((size_t)row << 6) + kt * 32 + 8 * g;
        const float* hp = h_norm + (size_t)row * h_stride + kt * 32 + 8 * g;
        float4 a0 = *reinterpret_cast<const float4*>(ap);
        float4 a1 = *reinterpret_cast<const float4*>(ap + 4);
        float4 h0 = *reinterpret_cast<const float4*>(hp);
        float4 h1 = *reinterpret_cast<const float4*>(hp + 4);
        bf16x8 af, mf;
        af[0] = (short)f2bf(a0.x); af[1] = (short)f2bf(a0.y);
        af[2] = (short)f2bf(a0.z); af[3] = (short)f2bf(a0.w);
        af[4] = (short)f2bf(a1.x); af[5] = (short)f2bf(a1.y);
        af[6] = (short)f2bf(a1.z); af[7] = (short)f2bf(a1.w);
        mf[0] = (short)f2bf(a0.x * h0.x * lv); mf[1] = (short)f2bf(a0.y * h0.y * lv);
        mf[2] = (short)f2bf(a0.z * h0.z * lv); mf[3] = (short)f2bf(a0.w * h0.w * lv);
        mf[4] = (short)f2bf(a1.x * h1.x * lv); mf[5] = (short)f2bf(a1.y * h1.y * lv);
        mf[6] = (short)f2bf(a1.z * h1.z * lv); mf[7] = (short)f2bf(a1.w * h1.w * lv);
#pragma unroll
        for (int dt = 0; dt < 4; ++dt) {
            acc1[dt] = __builtin_amdgcn_mfma_f32_16x16x32_bf16(af, w1f[kt][dt], acc1[dt], 0, 0, 0);
            acc2[dt] = __builtin_amdgcn_mfma_f32_16x16x32_bf16(mf, w2f[kt][dt], acc2[dt], 0, 0, 0);
        }
    }

    float b1v[4], b2v[4];
#pragma unroll
    for (int dt = 0; dt < 4; ++dt) {
        b1v[dt] = b1[dt * 16 + r16];
        b2v[dt] = b2[dt * 16 + r16];
    }
    float v[4][4];  // [dt][reg]
#pragma unroll
    for (int dt = 0; dt < 4; ++dt) {
#pragma unroll
        for (int reg = 0; reg < 4; ++reg) {
            float x1 = acc1[dt][reg] + b1v[dt];
            float x2 = acc2[dt][reg] + b2v[dt];
            x1 = x1 > 0.0f ? x1 : LEAKY * x1;
            x2 = x2 > 0.0f ? x2 : LEAKY * x2;
            v[dt][reg] = x1 + x2;
        }
    }
#pragma unroll
    for (int reg = 0; reg < 4; ++reg) {
        float sq = v[0][reg] * v[0][reg] + v[1][reg] * v[1][reg] +
                   v[2][reg] * v[2][reg] + v[3][reg] * v[3][reg];
        sq += __shfl_xor(sq, 1, 64);
        sq += __shfl_xor(sq, 2, 64);
        sq += __shfl_xor(sq, 4, 64);
        sq += __shfl_xor(sq, 8, 64);
        float m = fmaxf(sq, 1e-12f);
        float inv = rsqrtf(m);
        int orow = n0 + 4 * g + reg;
        if (orow < n_nodes) {
#pragma unroll
            for (int dt = 0; dt < 4; ++dt)
                out_norm[(size_t)orow * ostride + dt * 16 + r16] = v[dt][reg] * inv;
            if (r16 == reg) len_out[orow] = sqrtf(m);
        }
    }
}

// ---------------------------------------------------------------- copy x -> slot 0
__global__ __launch_bounds__(256) void copyx_kernel(const float* __restrict__ x,
                                                    float* __restrict__ out,
                                                    int n_nodes, int nslots) {
    int t = blockIdx.x * 256 + threadIdx.x;
    int total = n_nodes * 16;                 // 16 float4 per node row
    if (t >= total) return;
    int node = t >> 4;
    int j = t & 15;
    const float4* src = reinterpret_cast<const float4*>(x);
    float4* dst = reinterpret_cast<float4*>(out);
    dst[(size_t)node * (nslots * 16) + j] = src[(size_t)node * 16 + j];
}

// ---------------------------------------------------------------- launch
extern "C" void kernel_launch(void* const* d_in, const int* in_sizes, int n_in,
                              void* d_out, int out_size, void* d_ws, size_t ws_size,
                              hipStream_t stream) {
    const float* x  = (const float*)d_in[0];
    const int*  edge = (const int*)d_in[1];
    const float* W1 = (const float*)d_in[2];
    const float* b1 = (const float*)d_in[3];
    const float* W2 = (const float*)d_in[4];
    const float* b2 = (const float*)d_in[5];

    const int N = in_sizes[0] / 64;
    const int E = in_sizes[1] / 2;
    const int K = in_sizes[2] / 4096;
    const int nslots = K + 1;
    const int ostride = nslots * 64;

    const int* row = edge;
    const int* col = edge + E;
    float* out = (float*)d_out;

    char* ws = (char*)d_ws;
    size_t off = 0;
    auto carve = [&](size_t bytes) -> void* {
        void* p = ws + off;
        off = (off + bytes + 255) & ~(size_t)255;
        return p;
    };
    int*   deg     = (int*)  carve((size_t)N * 4);
    int*   rowptr  = (int*)  carve((size_t)(N + 1) * 4);
    int*   cursor  = (int*)  carve((size_t)N * 4);
    float* dinv    = (float*)carve((size_t)N * 4);
    float* scale   = (float*)carve((size_t)N * 4);
    float* len     = (float*)carve((size_t)N * 4);
    int*   cols_s  = (int*)  carve((size_t)E * 4);
    float* agg     = (float*)carve((size_t)N * 64 * 4);
    int*   bsums   = (int*)  carve(2048 * 4);
    (void)ws_size;

    hipMemsetAsync(deg, 0, (size_t)N * 4, stream);
    hipMemsetAsync(cursor, 0, (size_t)N * 4, stream);

    const int eblk8 = (E + 256 * 8 - 1) / (256 * 8);
    hist_kernel<<<eblk8, 256, 0, stream>>>(row, E, deg);

    const int nb = (N + 1 + SCAN_BS - 1) / SCAN_BS;
    bsum_kernel<<<nb, SCAN_BS, 0, stream>>>(deg, bsums, N);
    scan_bsums_kernel<<<1, 1024, 0, stream>>>(bsums, nb);
    rowptr_kernel<<<nb, SCAN_BS, 0, stream>>>(deg, bsums, rowptr, N);

    dinv_kernel<<<(N + 255) / 256, 256, 0, stream>>>(deg, dinv, N);
    scatter_kernel<<<eblk8, 256, 0, stream>>>(row, col, E, rowptr, cursor, cols_s);

    copyx_kernel<<<(N * 16 + 255) / 256, 256, 0, stream>>>(x, out, N, nslots);

    const int waves_needed = (N + 15) / 16;
    const int tblocks = (waves_needed + 3) / 4;
    const int nblk256 = (N + 255) / 256;

    for (int i = 0; i < K; ++i) {
        const float* h_norm;
        int h_stride;
        const float* len_in;
        const float* sc;
        if (i == 0) {
            h_norm = x; h_stride = 64; len_in = nullptr; sc = dinv;
        } else {
            h_norm = out + (size_t)i * 64; h_stride = ostride; len_in = len;
            scale_kernel<<<nblk256, 256, 0, stream>>>(dinv, len, scale, N);
            sc = scale;
        }
        aggregate_kernel<<<(N * 64 + 255) / 256, 256, 0, stream>>>(rowptr, cols_s, sc, dinv,
                                                                   h_norm, h_stride, agg, N);
        transform_kernel<<<tblocks, 256, 0, stream>>>(h_norm, h_stride, len_in, agg,
                                                      W1 + (size_t)i * 4096,
                                                      b1 + (size_t)i * 64,
                                                      W2 + (size_t)i * 4096,
                                                      b2 + (size_t)i * 64,
                                                      out + (size_t)(i + 1) * 64,
                                                      ostride, len, N);
    }
}

// Round 7
// 312.047 us; speedup vs baseline: 1.6473x; 1.1759x over previous
//
#include <hip/hip_runtime.h>

#define LEAKY 0.2f
#define SCAN_BS 256

typedef __attribute__((ext_vector_type(8))) short bf16x8;
typedef __attribute__((ext_vector_type(4))) float f32x4;

__device__ __forceinline__ unsigned short f2bf(float f) {
    unsigned u = __float_as_uint(f);
    u += 0x7FFF + ((u >> 16) & 1);          // RTNE
    return (unsigned short)(u >> 16);
}
__device__ __forceinline__ float bf2f(unsigned short u) {
    return __uint_as_float((unsigned)u << 16);
}

// ---------------------------------------------------------------- CSR build
// Pass 1: histogram whose atomic RETURN VALUE is the edge's rank in its row.
// 4 edges/thread -> 1250 blocks (TLP) with 4 independent atomic chains (ILP).
__global__ __launch_bounds__(256) void hist_rank_kernel(const int* __restrict__ row, int E,
                                                        int* __restrict__ deg,
                                                        int* __restrict__ rank) {
    int base = (blockIdx.x * 256 + threadIdx.x) * 4;
    if (base + 4 <= E) {
        int4 r = *reinterpret_cast<const int4*>(row + base);
        int4 k;
        k.x = atomicAdd(&deg[r.x], 1);
        k.y = atomicAdd(&deg[r.y], 1);
        k.z = atomicAdd(&deg[r.z], 1);
        k.w = atomicAdd(&deg[r.w], 1);
        *reinterpret_cast<int4*>(rank + base) = k;
    } else {
        for (int e = base; e < E; ++e) rank[e] = atomicAdd(&deg[row[e]], 1);
    }
}

__global__ __launch_bounds__(SCAN_BS) void bsum_kernel(const int* __restrict__ deg,
                                                       int* __restrict__ bsums, int n) {
    int i = blockIdx.x * SCAN_BS + threadIdx.x;
    int v = (i < n) ? deg[i] : 0;
    for (int off = 32; off; off >>= 1) v += __shfl_xor(v, off, 64);
    __shared__ int wsum[SCAN_BS / 64];
    int lane = threadIdx.x & 63, w = threadIdx.x >> 6;
    if (lane == 0) wsum[w] = v;
    __syncthreads();
    if (threadIdx.x == 0) {
        int s = 0;
#pragma unroll
        for (int j = 0; j < SCAN_BS / 64; ++j) s += wsum[j];
        bsums[blockIdx.x] = s;
    }
}

__global__ __launch_bounds__(1024) void scan_bsums_kernel(int* __restrict__ bsums, int nb) {
    __shared__ int sh[1024];
    int tid = threadIdx.x;
    int v = (tid < nb) ? bsums[tid] : 0;
    sh[tid] = v;
    __syncthreads();
    for (int off = 1; off < 1024; off <<= 1) {
        int u = (tid >= off) ? sh[tid - off] : 0;
        __syncthreads();
        sh[tid] += u;
        __syncthreads();
    }
    if (tid < nb) bsums[tid] = sh[tid] - v;  // exclusive
}

__global__ __launch_bounds__(SCAN_BS) void rowptr_kernel(const int* __restrict__ deg,
                                                         const int* __restrict__ bsums_ex,
                                                         int* __restrict__ rowptr, int n) {
    __shared__ int sh[SCAN_BS];
    int tid = threadIdx.x;
    int i = blockIdx.x * SCAN_BS + tid;
    int v = (i < n) ? deg[i] : 0;
    sh[tid] = v;
    __syncthreads();
    for (int off = 1; off < SCAN_BS; off <<= 1) {
        int u = (tid >= off) ? sh[tid - off] : 0;
        __syncthreads();
        sh[tid] += u;
        __syncthreads();
    }
    if (i <= n) rowptr[i] = sh[tid] - v + bsums_ex[blockIdx.x];
}

__global__ __launch_bounds__(256) void dinv_kernel(const int* __restrict__ deg,
                                                   float* __restrict__ dinv, int n) {
    int i = blockIdx.x * 256 + threadIdx.x;
    if (i < n) {
        int d = deg[i];
        dinv[i] = d > 0 ? rsqrtf((float)d) : 0.0f;
    }
}

// Pass 2: atomic-free placement: p = rowptr[row[e]] + rank[e].
__global__ __launch_bounds__(256) void scatter_store_kernel(const int* __restrict__ row,
                                                            const int* __restrict__ col,
                                                            const int* __restrict__ rank, int E,
                                                            const int* __restrict__ rowptr,
                                                            int* __restrict__ cols_s) {
    int base = (blockIdx.x * 256 + threadIdx.x) * 4;
    if (base + 4 <= E) {
        int4 r = *reinterpret_cast<const int4*>(row + base);
        int4 c = *reinterpret_cast<const int4*>(col + base);
        int4 k = *reinterpret_cast<const int4*>(rank + base);
        int p0 = rowptr[r.x];
        int p1 = rowptr[r.y];
        int p2 = rowptr[r.z];
        int p3 = rowptr[r.w];
        cols_s[p0 + k.x] = c.x;
        cols_s[p1 + k.y] = c.y;
        cols_s[p2 + k.z] = c.z;
        cols_s[p3 + k.w] = c.w;
    } else {
        for (int e = base; e < E; ++e) cols_s[rowptr[row[e]] + rank[e]] = col[e];
    }
}

__global__ __launch_bounds__(256) void scale_kernel(const float* __restrict__ dinv,
                                                    const float* __restrict__ len,
                                                    float* __restrict__ scale, int n) {
    int i = blockIdx.x * 256 + threadIdx.x;
    if (i < n) scale[i] = dinv[i] * len[i];
}

// ---------------------------------------------------------------- aggregate
// one wave per node, lane = feature dim; bf16 feature table halves the gather
// traffic (128B/edge); 8 independent gathers in flight; f32 accumulate.
__global__ __launch_bounds__(256) void aggregate_kernel(const int* __restrict__ rowptr,
                                                        const int* __restrict__ cols_s,
                                                        const float* __restrict__ scale,
                                                        const float* __restrict__ dinv,
                                                        const unsigned short* __restrict__ h_bf,
                                                        float* __restrict__ agg,
                                                        int n_nodes) {
    int lane = threadIdx.x & 63;
    int n = (blockIdx.x * blockDim.x + threadIdx.x) >> 6;
    if (n >= n_nodes) return;
    int nu = __builtin_amdgcn_readfirstlane(n);
    int s = rowptr[nu];
    int e = rowptr[nu + 1];
    float dn = dinv[nu];
    float acc0 = 0.0f, acc1 = 0.0f, acc2 = 0.0f, acc3 = 0.0f;
    int t = s;
    for (; t + 7 < e; t += 8) {
        int c[8];
        float w[8];
#pragma unroll
        for (int j = 0; j < 8; ++j) c[j] = cols_s[t + j];
#pragma unroll
        for (int j = 0; j < 8; ++j) w[j] = scale[c[j]];
        float hv[8];
#pragma unroll
        for (int j = 0; j < 8; ++j) hv[j] = bf2f(h_bf[((size_t)c[j] << 6) + lane]);
        acc0 = fmaf(w[0], hv[0], acc0);
        acc1 = fmaf(w[1], hv[1], acc1);
        acc2 = fmaf(w[2], hv[2], acc2);
        acc3 = fmaf(w[3], hv[3], acc3);
        acc0 = fmaf(w[4], hv[4], acc0);
        acc1 = fmaf(w[5], hv[5], acc1);
        acc2 = fmaf(w[6], hv[6], acc2);
        acc3 = fmaf(w[7], hv[7], acc3);
    }
    if (t + 3 < e) {
        int c0 = cols_s[t + 0];
        int c1 = cols_s[t + 1];
        int c2 = cols_s[t + 2];
        int c3 = cols_s[t + 3];
        float w0 = scale[c0];
        float w1 = scale[c1];
        float w2 = scale[c2];
        float w3 = scale[c3];
        acc0 = fmaf(w0, bf2f(h_bf[((size_t)c0 << 6) + lane]), acc0);
        acc1 = fmaf(w1, bf2f(h_bf[((size_t)c1 << 6) + lane]), acc1);
        acc2 = fmaf(w2, bf2f(h_bf[((size_t)c2 << 6) + lane]), acc2);
        acc3 = fmaf(w3, bf2f(h_bf[((size_t)c3 << 6) + lane]), acc3);
        t += 4;
    }
    for (; t < e; ++t) {
        int c0 = cols_s[t];
        acc0 = fmaf(scale[c0], bf2f(h_bf[((size_t)c0 << 6) + lane]), acc0);
    }
    agg[((size_t)n << 6) + lane] = dn * ((acc0 + acc1) + (acc2 + acc3));
}

// ---------------------------------------------------------------- transform (MFMA)
// One wave = 16-node x 64-dim output tile. C1 = A*W1, C2 = M*W2 with
// A = agg tile, M = agg .* (h_bf*len), via v_mfma_f32_16x16x32_bf16.
// Epilogue: bias + leaky + fused l2-norm; writes fp32 out row + bf16 h row.
__global__ __launch_bounds__(256, 3) void transform_kernel(const unsigned short* __restrict__ h_bf,
                                                           const float* __restrict__ len_in,
                                                           const float* __restrict__ agg,
                                                           const float* __restrict__ w1,
                                                           const float* __restrict__ b1,
                                                           const float* __restrict__ w2,
                                                           const float* __restrict__ b2,
                                                           float* __restrict__ out_norm,
                                                           int ostride,
                                                           float* __restrict__ len_out,
                                                           unsigned short* __restrict__ hbf_out,
                                                           int n_nodes) {
    int lane = threadIdx.x & 63;
    int wave = (blockIdx.x * blockDim.x + threadIdx.x) >> 6;
    int n0 = wave * 16;
    if (n0 >= n_nodes) return;

    int r16 = lane & 15;   // A row / B,C col within tile
    int g   = lane >> 4;   // k-group

    bf16x8 w1f[2][4], w2f[2][4];
#pragma unroll
    for (int kt = 0; kt < 2; ++kt) {
#pragma unroll
        for (int dt = 0; dt < 4; ++dt) {
            const float* p1 = w1 + (kt * 32 + 8 * g) * 64 + dt * 16 + r16;
            const float* p2 = w2 + (kt * 32 + 8 * g) * 64 + dt * 16 + r16;
            bf16x8 f1, f2;
#pragma unroll
            for (int j = 0; j < 8; ++j) {
                f1[j] = (short)f2bf(p1[(size_t)j * 64]);
                f2[j] = (short)f2bf(p2[(size_t)j * 64]);
            }
            w1f[kt][dt] = f1;
            w2f[kt][dt] = f2;
        }
    }

    int row = n0 + r16;
    if (row >= n_nodes) row = n_nodes - 1;          // clamp for tail tile
    float lv = len_in ? len_in[row] : 1.0f;

    f32x4 acc1[4], acc2[4];
#pragma unroll
    for (int dt = 0; dt < 4; ++dt) {
        acc1[dt] = (f32x4){0.0f, 0.0f, 0.0f, 0.0f};
        acc2[dt] = (f32x4){0.0f, 0.0f, 0.0f, 0.0f};
    }

#pragma unroll
    for (int kt = 0; kt < 2; ++kt) {
        const float* ap = agg + ((size_t)row << 6) + kt * 32 + 8 * g;
        const unsigned short* hp = h_bf + ((size_t)row << 6) + kt * 32 + 8 * g;
        float4 a0 = *reinterpret_cast<const float4*>(ap);
        float4 a1 = *reinterpret_cast<const float4*>(ap + 4);
        bf16x8 h8 = *reinterpret_cast<const bf16x8*>(hp);
        float af32[8] = {a0.x, a0.y, a0.z, a0.w, a1.x, a1.y, a1.z, a1.w};
        bf16x8 af, mf;
#pragma unroll
        for (int j = 0; j < 8; ++j) {
            af[j] = (short)f2bf(af32[j]);
            mf[j] = (short)f2bf(af32[j] * bf2f((unsigned short)h8[j]) * lv);
        }
#pragma unroll
        for (int dt = 0; dt < 4; ++dt) {
            acc1[dt] = __builtin_amdgcn_mfma_f32_16x16x32_bf16(af, w1f[kt][dt], acc1[dt], 0, 0, 0);
            acc2[dt] = __builtin_amdgcn_mfma_f32_16x16x32_bf16(mf, w2f[kt][dt], acc2[dt], 0, 0, 0);
        }
    }

    float b1v[4], b2v[4];
#pragma unroll
    for (int dt = 0; dt < 4; ++dt) {
        b1v[dt] = b1[dt * 16 + r16];
        b2v[dt] = b2[dt * 16 + r16];
    }
    float v[4][4];  // [dt][reg]
#pragma unroll
    for (int dt = 0; dt < 4; ++dt) {
#pragma unroll
        for (int reg = 0; reg < 4; ++reg) {
            float x1 = acc1[dt][reg] + b1v[dt];
            float x2 = acc2[dt][reg] + b2v[dt];
            x1 = x1 > 0.0f ? x1 : LEAKY * x1;
            x2 = x2 > 0.0f ? x2 : LEAKY * x2;
            v[dt][reg] = x1 + x2;
        }
    }
#pragma unroll
    for (int reg = 0; reg < 4; ++reg) {
        float sq = v[0][reg] * v[0][reg] + v[1][reg] * v[1][reg] +
                   v[2][reg] * v[2][reg] + v[3][reg] * v[3][reg];
        sq += __shfl_xor(sq, 1, 64);
        sq += __shfl_xor(sq, 2, 64);
        sq += __shfl_xor(sq, 4, 64);
        sq += __shfl_xor(sq, 8, 64);
        float m = fmaxf(sq, 1e-12f);
        float inv = rsqrtf(m);
        int orow = n0 + 4 * g + reg;
        if (orow < n_nodes) {
#pragma unroll
            for (int dt = 0; dt < 4; ++dt) {
                float nv = v[dt][reg] * inv;
                out_norm[(size_t)orow * ostride + dt * 16 + r16] = nv;
                hbf_out[((size_t)orow << 6) + dt * 16 + r16] = f2bf(nv);
            }
            if (r16 == reg) len_out[orow] = sqrtf(m);
        }
    }
}

// ---------------------------------------------------------------- copy x -> slot 0 (+ bf16 table)
__global__ __launch_bounds__(256) void copyx_kernel(const float* __restrict__ x,
                                                    float* __restrict__ out,
                                                    unsigned short* __restrict__ x_bf,
                                                    int n_nodes, int nslots) {
    int t = blockIdx.x * 256 + threadIdx.x;
    int total = n_nodes * 16;                 // 16 float4 per node row
    if (t >= total) return;
    int node = t >> 4;
    int j = t & 15;
    float4 v = reinterpret_cast<const float4*>(x)[(size_t)node * 16 + j];
    reinterpret_cast<float4*>(out)[(size_t)node * (nslots * 16) + j] = v;
    ushort4 b;
    b.x = f2bf(v.x); b.y = f2bf(v.y); b.z = f2bf(v.z); b.w = f2bf(v.w);
    reinterpret_cast<ushort4*>(x_bf)[(size_t)node * 16 + j] = b;
}

// ---------------------------------------------------------------- launch
extern "C" void kernel_launch(void* const* d_in, const int* in_sizes, int n_in,
                              void* d_out, int out_size, void* d_ws, size_t ws_size,
                              hipStream_t stream) {
    const float* x  = (const float*)d_in[0];
    const int*  edge = (const int*)d_in[1];
    const float* W1 = (const float*)d_in[2];
    const float* b1 = (const float*)d_in[3];
    const float* W2 = (const float*)d_in[4];
    const float* b2 = (const float*)d_in[5];

    const int N = in_sizes[0] / 64;
    const int E = in_sizes[1] / 2;
    const int K = in_sizes[2] / 4096;
    const int nslots = K + 1;
    const int ostride = nslots * 64;

    const int* row = edge;
    const int* col = edge + E;
    float* out = (float*)d_out;

    char* ws = (char*)d_ws;
    size_t off = 0;
    auto carve = [&](size_t bytes) -> void* {
        void* p = ws + off;
        off = (off + bytes + 255) & ~(size_t)255;
        return p;
    };
    int*   deg     = (int*)  carve((size_t)N * 4);
    int*   rowptr  = (int*)  carve((size_t)(N + 1) * 4);
    float* dinv    = (float*)carve((size_t)N * 4);
    float* scale   = (float*)carve((size_t)N * 4);
    float* len     = (float*)carve((size_t)N * 4);
    int*   rank    = (int*)  carve((size_t)E * 4);
    int*   cols_s  = (int*)  carve((size_t)E * 4);
    float* agg     = (float*)carve((size_t)N * 64 * 4);
    unsigned short* hbfA = (unsigned short*)carve((size_t)N * 64 * 2);
    unsigned short* hbfB = (unsigned short*)carve((size_t)N * 64 * 2);
    int*   bsums   = (int*)  carve(2048 * 4);
    (void)ws_size;

    hipMemsetAsync(deg, 0, (size_t)N * 4, stream);

    const int eblk4 = (E + 256 * 4 - 1) / (256 * 4);
    hist_rank_kernel<<<eblk4, 256, 0, stream>>>(row, E, deg, rank);

    const int nb = (N + 1 + SCAN_BS - 1) / SCAN_BS;
    bsum_kernel<<<nb, SCAN_BS, 0, stream>>>(deg, bsums, N);
    scan_bsums_kernel<<<1, 1024, 0, stream>>>(bsums, nb);
    rowptr_kernel<<<nb, SCAN_BS, 0, stream>>>(deg, bsums, rowptr, N);

    dinv_kernel<<<(N + 255) / 256, 256, 0, stream>>>(deg, dinv, N);
    scatter_store_kernel<<<eblk4, 256, 0, stream>>>(row, col, rank, E, rowptr, cols_s);

    copyx_kernel<<<(N * 16 + 255) / 256, 256, 0, stream>>>(x, out, hbfA, N, nslots);

    const int waves_needed = (N + 15) / 16;
    const int tblocks = (waves_needed + 3) / 4;
    const int nblk256 = (N + 255) / 256;

    unsigned short* hin = hbfA;
    unsigned short* hout = hbfB;
    for (int i = 0; i < K; ++i) {
        const float* len_in;
        const float* sc;
        if (i == 0) {
            len_in = nullptr; sc = dinv;
        } else {
            len_in = len;
            scale_kernel<<<nblk256, 256, 0, stream>>>(dinv, len, scale, N);
            sc = scale;
        }
        aggregate_kernel<<<(N * 64 + 255) / 256, 256, 0, stream>>>(rowptr, cols_s, sc, dinv,
                                                                   hin, agg, N);
        transform_kernel<<<tblocks, 256, 0, stream>>>(hin, len_in, agg,
                                                      W1 + (size_t)i * 4096,
                                                      b1 + (size_t)i * 64,
                                                      W2 + (size_t)i * 4096,
                                                      b2 + (size_t)i * 64,
                                                      out + (size_t)(i + 1) * 64,
                                                      ostride, len, hout, N);
        unsigned short* tmp = hin; hin = hout; hout = tmp;
    }
}